// Round 1
// 376.662 us; speedup vs baseline: 1.0766x; 1.0766x over previous
//
#include <hip/hip_runtime.h>

// Problem constants (fixed by the reference)
#define Bdim   8
#define Cdim   2
#define Fdim   1024
#define Tdim   1024
#define NB     64
#define BWb    16
#define EMB    128
#define FEAT   64      // C * BW * 2
#define TILE_T 64
#define NTHR   256
#define EPSV   1e-5f

// MFMA fragment types (guide §3: 8 bf16 = 4 VGPRs, 4 f32 accum)
typedef __attribute__((ext_vector_type(8))) short bf16x8;
typedef __attribute__((ext_vector_type(4))) float f32x4;

// round-to-nearest-even fp32 -> bf16 (values are finite, no NaN handling needed)
__device__ __forceinline__ unsigned short f2bf(float x) {
    union { float f; unsigned u; } v; v.f = x;
    const unsigned r = v.u + 0x7FFFu + ((v.u >> 16) & 1u);
    return (unsigned short)(r >> 16);
}
__device__ __forceinline__ float bf2f(unsigned short b) {
    union { float f; unsigned u; } v; v.u = ((unsigned)b) << 16;
    return v.f;
}

// Grid: Bdim * NB * (Tdim/TILE_T) = 8192 blocks of 256 threads (4 waves).
// Per block: one (b, n) band, 64 t values. GEMM (64t x 64f x 128e) runs on
// matrix cores as a 3-pass bf16 hi/lo split (Ahi*Whi + Ahi*Wlo + Alo*Whi),
// error ~2^-17 relative — negligible vs the existing 0.0078 absmax.
// LDS: xs 16KB (overlaid by A hi/lo bf16 after LN) + W hi/lo 32KB + 1.5KB
//   = 49.5KB -> 3 blocks/CU.
__global__ __launch_bounds__(NTHR, 3) void bandsplit_kernel(
    const float* __restrict__ xr, const float* __restrict__ xi,
    const float* __restrict__ lnw, const float* __restrict__ lnb,
    const float* __restrict__ fcw, const float* __restrict__ fcb,
    float* __restrict__ out)
{
    // xs[f][t] fp32 for staging+stats; after LN it is overlaid by
    //   a_hi (bytes [0,8192), bf16 [t=64][f=64]) and a_lo (bytes [8192,16384)).
    __shared__ __align__(16) float xs[FEAT][TILE_T];            // 16 KB
    __shared__ __align__(16) unsigned short w_hi[EMB][FEAT];    // 16 KB, [e][f]
    __shared__ __align__(16) unsigned short w_lo[EMB][FEAT];    // 16 KB, [e][f]
    __shared__ float sb[EMB];
    __shared__ float slnw[FEAT];
    __shared__ float slnb[FEAT];
    __shared__ float smu[TILE_T];
    __shared__ float srs[TILE_T];

    const int tid  = threadIdx.x;
    const int lane = tid & 63;
    const int wav  = tid >> 6;
    const int bid  = blockIdx.x;
    const int tb   = bid & 15;          // t-tile
    const int n    = (bid >> 4) & 63;   // band
    const int b    = bid >> 10;         // batch
    const int t0g  = tb * TILE_T;

    // ---- Phase 1: stage x tile (fp32 [f][t], coalesced along t) ----
#pragma unroll
    for (int k = 0; k < 4; ++k) {
        const int v  = tid + k * NTHR;      // 0..1023
        const int f  = v >> 4;              // 0..63
        const int tq = v & 15;
        const int c  = f >> 5;
        const int w  = (f >> 1) & 15;
        const float* src = ((f & 1) ? xi : xr)
            + (((size_t)(b * Cdim + c) * Fdim + (n * BWb + w)) * Tdim + t0g + tq * 4);
        *(float4*)&xs[f][tq * 4] = *(const float4*)src;
    }

    if (tid < EMB)            sb[tid]              = fcb[n * EMB + tid];
    else if (tid < EMB + 64)  slnw[tid - EMB]      = lnw[n * FEAT + (tid - EMB)];
    else if (tid < EMB + 128) slnb[tid - EMB - 64] = lnb[n * FEAT + (tid - EMB - 64)];

    // ---- Phase 1b: W -> bf16 hi/lo, transposed [e][f], XOR-swizzled chunks.
    // lanes = consecutive e => coalesced 256B global reads (L2-resident).
    // Chunk swizzle cs = chunk ^ (e&7): fragment reads/writes spread 8 lanes
    // per bank-quad (optimal for b128).
    {
        const int e  = tid & 127;           // 0..127
        const int fh = (tid >> 7) * 32;     // f half: 0 or 32
        const float* wsrc = fcw + (size_t)n * FEAT * EMB + e;
        float wv[32];
#pragma unroll
        for (int i = 0; i < 32; ++i)
            wv[i] = wsrc[(size_t)(fh + i) * EMB];

        char* const whb = (char*)&w_hi[0][0] + e * 128;
        char* const wlb = (char*)&w_lo[0][0] + e * 128;
#pragma unroll
        for (int cc = 0; cc < 4; ++cc) {
            unsigned hw[4], lw[4];
#pragma unroll
            for (int j = 0; j < 4; ++j) {
                const float x0 = wv[cc * 8 + 2 * j];
                const float x1 = wv[cc * 8 + 2 * j + 1];
                const unsigned short h0 = f2bf(x0), h1 = f2bf(x1);
                hw[j] = (unsigned)h0 | ((unsigned)h1 << 16);
                lw[j] = (unsigned)f2bf(x0 - bf2f(h0))
                      | ((unsigned)f2bf(x1 - bf2f(h1)) << 16);
            }
            const int cs = ((fh >> 3) + cc) ^ (e & 7);
            *(uint4*)(whb + cs * 16) = make_uint4(hw[0], hw[1], hw[2], hw[3]);
            *(uint4*)(wlb + cs * 16) = make_uint4(lw[0], lw[1], lw[2], lw[3]);
        }
    }
    __syncthreads();

    // ---- Phase 2: per-row LN stats (4 lanes per t, shuffle-combine) ----
    {
        const int t = tid >> 2;
        const int p = tid & 3;
        float s = 0.f, ss = 0.f;
#pragma unroll
        for (int j = 0; j < 16; ++j) {
            const float v = xs[p * 16 + j][t];
            s += v; ss += v * v;
        }
        s += __shfl_xor(s, 1); ss += __shfl_xor(ss, 1);
        s += __shfl_xor(s, 2); ss += __shfl_xor(ss, 2);
        if (p == 0) {
            const float mu  = s * (1.f / 64.f);
            const float var = ss * (1.f / 64.f) - mu * mu;
            smu[t] = mu;
            srs[t] = rsqrtf(var + EPSV);
        }
    }
    __syncthreads();

    // ---- Phase 3: normalize + transpose + bf16 hi/lo split.
    // Reads xs column-wise (64 lanes = 64 distinct t -> 2-way, free), holds
    // results in regs, then barrier, then overlay-writes A into xs's bytes.
    uint4 hq[2], lq[2];
    {
        const int t = lane;
        const float mu = smu[t], rs = srs[t];
#pragma unroll
        for (int u = 0; u < 2; ++u) {
            const int fc = wav + u * 4;     // f-chunk 0..7
            float xv[8];
#pragma unroll
            for (int j = 0; j < 8; ++j) xv[j] = xs[fc * 8 + j][t];
            unsigned hw[4], lw[4];
#pragma unroll
            for (int j = 0; j < 4; ++j) {
                const int f0 = fc * 8 + 2 * j;
                const float xn0 = (xv[2 * j]     - mu) * rs * slnw[f0]     + slnb[f0];
                const float xn1 = (xv[2 * j + 1] - mu) * rs * slnw[f0 + 1] + slnb[f0 + 1];
                const unsigned short h0 = f2bf(xn0), h1 = f2bf(xn1);
                hw[j] = (unsigned)h0 | ((unsigned)h1 << 16);
                lw[j] = (unsigned)f2bf(xn0 - bf2f(h0))
                      | ((unsigned)f2bf(xn1 - bf2f(h1)) << 16);
            }
            hq[u] = make_uint4(hw[0], hw[1], hw[2], hw[3]);
            lq[u] = make_uint4(lw[0], lw[1], lw[2], lw[3]);
        }
    }
    __syncthreads();   // every thread finished reading xs -> safe to overlay

    {
        char* const ab = (char*)&xs[0][0];
        const int t = lane;
#pragma unroll
        for (int u = 0; u < 2; ++u) {
            const int fc = wav + u * 4;
            const int cs = fc ^ (t & 7);
            *(uint4*)(ab +        t * 128 + cs * 16) = hq[u];   // a_hi[t][fc*8..]
            *(uint4*)(ab + 8192 + t * 128 + cs * 16) = lq[u];   // a_lo[t][fc*8..]
        }
    }
    __syncthreads();

    // ---- Phase 4: MFMA GEMM. Wave w owns t rows [16w,16w+16) x all 128 e.
    // 16x16x32 bf16 layouts (m89/m91-verified):
    //   A: row = lane&15 (t), k = (lane>>4)*8 + j (contiguous 16B)
    //   B: col = lane&15 (e), k = (lane>>4)*8 + j  <- read from wT[e][k]
    //   D: col = lane&15 (e), row = (lane>>4)*4 + reg (t)
    const int lr   = lane & 15;
    const int lh   = lane >> 4;
    const int trow = wav * 16;

    f32x4 acc[8];
    const f32x4 zero = {0.f, 0.f, 0.f, 0.f};
#pragma unroll
    for (int et = 0; et < 8; ++et) acc[et] = zero;

    const char* const ab  = (const char*)&xs[0][0];
    const char* const whb = (const char*)&w_hi[0][0];
    const char* const wlb = (const char*)&w_lo[0][0];

#pragma unroll
    for (int ks = 0; ks < 2; ++ks) {
        const int ta = trow + lr;
        const int ca = (ks * 4 + lh) ^ (ta & 7);
        const bf16x8 ahf = *(const bf16x8*)(ab +        ta * 128 + ca * 16);
        const bf16x8 alf = *(const bf16x8*)(ab + 8192 + ta * 128 + ca * 16);
#pragma unroll
        for (int et = 0; et < 8; ++et) {
            const int er = et * 16 + lr;
            const int cw = (ks * 4 + lh) ^ (er & 7);
            const bf16x8 whf = *(const bf16x8*)(whb + er * 128 + cw * 16);
            const bf16x8 wlf = *(const bf16x8*)(wlb + er * 128 + cw * 16);
            acc[et] = __builtin_amdgcn_mfma_f32_16x16x32_bf16(ahf, whf, acc[et], 0, 0, 0);
            acc[et] = __builtin_amdgcn_mfma_f32_16x16x32_bf16(ahf, wlf, acc[et], 0, 0, 0);
            acc[et] = __builtin_amdgcn_mfma_f32_16x16x32_bf16(alf, whf, acc[et], 0, 0, 0);
        }
    }

    // ---- Epilogue: bias + stores. Per instr: 4 rows x 16 lanes x 4B = 64B
    // contiguous segments -> fully coalesced at the 64B granule.
    const size_t obase = ((size_t)(b * NB + n) * Tdim + (t0g + trow + lh * 4)) * EMB;
#pragma unroll
    for (int et = 0; et < 8; ++et) {
        const int   ec = et * 16 + lr;
        const float be = sb[ec];
#pragma unroll
        for (int r = 0; r < 4; ++r)
            out[obase + (size_t)r * EMB + ec] = acc[et][r] + be;
    }
}

extern "C" void kernel_launch(void* const* d_in, const int* in_sizes, int n_in,
                              void* d_out, int out_size, void* d_ws, size_t ws_size,
                              hipStream_t stream) {
    const float* xr  = (const float*)d_in[0];
    const float* xi  = (const float*)d_in[1];
    const float* lnw = (const float*)d_in[2];
    const float* lnb = (const float*)d_in[3];
    const float* fcw = (const float*)d_in[4];
    const float* fcb = (const float*)d_in[5];
    float* out = (float*)d_out;

    const int grid = Bdim * NB * (Tdim / TILE_T);   // 8192
    hipLaunchKernelGGL(bandsplit_kernel, dim3(grid), dim3(NTHR), 0, stream,
                       xr, xi, lnw, lnb, fcw, fcb, out);
}